// Round 10
// baseline (318.584 us; speedup 1.0000x reference)
//
#include <hip/hip_runtime.h>
#include <hip/hip_fp8.h>

#define B_ 2048
#define D_ 512
#define V_ 50304
#define NROWB 16            // 2048 / 128
#define NCOLB 393           // 50304 / 128 panels
#define NWG (NROWB * NCOLB) // 6288 = 8 * 786
#define NCOPY 32
#define LOG2E 1.44269504088896340736f
#define LN2 0.69314718055994530942f

typedef __attribute__((ext_vector_type(16))) float f32x16;
typedef __attribute__((ext_vector_type(8))) int v8i;
typedef unsigned char u8;

__device__ inline unsigned f2bf(float f) {
  unsigned u = __float_as_uint(f);
  u += 0x7fffu + ((u >> 16) & 1u);
  return u >> 16;
}

// ---------------- transposing cast fp32 -> fp8 e4m3 (classifiers) ----------------
// 32-B chunk i = ((p*8 + kc)*2 + h)*128 + c : col c of panel p, k = kc*64 + h*32 + [0..32)
// B-fragment for lane l, tile col base cb: p*65536 + kc*8192 + (l>>5)*4096 + (cb + (l&31))*32
__global__ void cast8t_kernel(const float* __restrict__ src, uint4* __restrict__ dst,
                              float scale, int nchunk) {
  int i = blockIdx.x * blockDim.x + threadIdx.x;
  if (i >= nchunk) return;
  int c = i & 127;
  int h = (i >> 7) & 1;
  int kc = (i >> 8) & 7;
  int p = i >> 11;
  const float4* s = (const float4*)(src + (size_t)(p * 128 + c) * 512 + kc * 64 + h * 32);
  union { u8 b[32]; uint4 u[2]; } o;
#pragma unroll
  for (int q = 0; q < 8; ++q) {
    float4 f = s[q];
    o.b[q * 4 + 0] = __hip_fp8_e4m3(f.x * scale).__x;
    o.b[q * 4 + 1] = __hip_fp8_e4m3(f.y * scale).__x;
    o.b[q * 4 + 2] = __hip_fp8_e4m3(f.z * scale).__x;
    o.b[q * 4 + 3] = __hip_fp8_e4m3(f.w * scale).__x;
  }
  dst[2 * i] = o.u[0];
  dst[2 * i + 1] = o.u[1];
}

// ---------------- plain cast fp32 -> fp8 e4m3 (hidden, row-major) ----------------
__global__ void cast8_kernel(const float* __restrict__ src, uint2* __restrict__ dst,
                             float scale, int n8) {
  int i = blockIdx.x * blockDim.x + threadIdx.x;
  int stride = gridDim.x * blockDim.x;
  const float4* s4 = (const float4*)src;
  for (; i < n8; i += stride) {
    float4 a = s4[2 * i], b = s4[2 * i + 1];
    union { u8 c[8]; uint2 u; } p;
    p.c[0] = __hip_fp8_e4m3(a.x * scale).__x;
    p.c[1] = __hip_fp8_e4m3(a.y * scale).__x;
    p.c[2] = __hip_fp8_e4m3(a.z * scale).__x;
    p.c[3] = __hip_fp8_e4m3(a.w * scale).__x;
    p.c[4] = __hip_fp8_e4m3(b.x * scale).__x;
    p.c[5] = __hip_fp8_e4m3(b.y * scale).__x;
    p.c[6] = __hip_fp8_e4m3(b.z * scale).__x;
    p.c[7] = __hip_fp8_e4m3(b.w * scale).__x;
    dst[i] = p.u;
  }
}

// ---------------- exact fp32 target logit (one wave per row) ----------------
__global__ void tgt_kernel(const float* __restrict__ sh, const float* __restrict__ sc,
                           const int* __restrict__ targets, float* __restrict__ tgt_out) {
  int gid = blockIdx.x * blockDim.x + threadIdx.x;
  int w = gid >> 6, lane = gid & 63;
  if (w >= B_) return;
  int tgt = targets[w];
  const float4* a = (const float4*)(sh + (size_t)w * D_);
  const float4* b = (const float4*)(sc + (size_t)tgt * D_);
  float acc = 0.f;
#pragma unroll
  for (int i = 0; i < 2; ++i) {
    float4 x = a[lane + i * 64], y = b[lane + i * 64];
    acc += x.x * y.x + x.y * y.y + x.z * y.z + x.w * y.w;
  }
#pragma unroll
  for (int off = 1; off < 64; off <<= 1) acc += __shfl_xor(acc, off);
  if (lane == 0) tgt_out[w] = acc;
}

// ---------------- fused dual-GEMM, MX-fp8 32x32x64, 8 waves x 64x64, 4 waves/SIMD ----------------
__global__ __launch_bounds__(512, 4) void lce_main(
    const u8* __restrict__ SH8, const u8* __restrict__ TH8,
    const u8* __restrict__ SC8t, const u8* __restrict__ TC8t,
    float* __restrict__ stats32) {
  __shared__ __align__(16) uint exch[8192];   // 32 KB bf16-pair student logits
  __shared__ float pss[2][2][64];             // [wr][wc][row] partials
  __shared__ float pst[2][2][64];
  __shared__ float pat[2][2][64];

  const int tid = threadIdx.x;
  const int lane = tid & 63, w = tid >> 6;
  const int wq = w & 3;         // geometry: wr = wq>>1, wc = wq&1
  const int mat = w >> 2;       // 0 = student (waves 0-3), 1 = teacher (waves 4-7)
  const int wr = wq >> 1;
  const int wc = wq & 1;
  const int l5 = lane & 31;
  const int hi = lane >> 5;

  // XCD-aware bijective swizzle: 6288 = 8 * 786
  const int hw = blockIdx.x;
  const int lid = (hw & 7) * 786 + (hw >> 3);
  const int row0 = (lid & 15) * 128;
  const int p = lid >> 4;       // col panel
  const int jcopy = (hw & 7) * 4 + (p & 3);
  float* stats = stats32 + (size_t)jcopy * B_ * 3;

  // per-lane fragment bases (32-B contiguous per lane)
  const u8* gA = (mat ? TH8 : SH8) + (size_t)(row0 + wr * 64 + l5) * D_ + hi * 32;
  const u8* gB = (mat ? TC8t : SC8t) + (size_t)p * 65536 + hi * 4096 + (wc * 64 + l5) * 32;

  f32x16 acc[2][2];
#pragma unroll
  for (int mi = 0; mi < 2; ++mi)
#pragma unroll
    for (int ni = 0; ni < 2; ++ni)
#pragma unroll
      for (int e = 0; e < 16; ++e) acc[mi][ni][e] = 0.f;

#pragma unroll
  for (int kc = 0; kc < 8; ++kc) {
    v8i av[2], bv[2];
#pragma unroll
    for (int mi = 0; mi < 2; ++mi)
      av[mi] = *(const v8i*)(gA + (size_t)(mi * 32) * D_ + kc * 64);
#pragma unroll
    for (int ni = 0; ni < 2; ++ni)
      bv[ni] = *(const v8i*)(gB + kc * 8192 + ni * 1024);

    __builtin_amdgcn_s_setprio(1);
#pragma unroll
    for (int mi = 0; mi < 2; ++mi)
#pragma unroll
      for (int ni = 0; ni < 2; ++ni)
        acc[mi][ni] = __builtin_amdgcn_mfma_scale_f32_32x32x64_f8f6f4(
            av[mi], bv[ni], acc[mi][ni], 0, 0, 0, 127, 0, 127);
    __builtin_amdgcn_s_setprio(0);
  }

  // ---------------- epilogue ----------------
  // C/D layout (32x32): col = lane&31, row = (reg&3) + 8*(reg>>2) + 4*hi
  const float inv = 1.0f / 256.0f;  // acc = logit * 256 * LOG2E

  if (mat == 0) {
#pragma unroll
    for (int mi = 0; mi < 2; ++mi)
#pragma unroll
      for (int ni = 0; ni < 2; ++ni)
#pragma unroll
        for (int rp = 0; rp < 8; ++rp) {
          uint u = f2bf(acc[mi][ni][2 * rp] * inv) |
                   (f2bf(acc[mi][ni][2 * rp + 1] * inv) << 16);
          exch[(((wq * 2 + mi) * 2 + ni) * 8 + rp) * 64 + lane] = u;
        }
  }
  __syncthreads();

  if (mat == 0) {
#pragma unroll
    for (int mi = 0; mi < 2; ++mi)
#pragma unroll
      for (int rp = 0; rp < 8; ++rp) {
        float v0 = __builtin_amdgcn_exp2f(acc[mi][0][2 * rp] * inv) +
                   __builtin_amdgcn_exp2f(acc[mi][1][2 * rp] * inv);
        float v1 = __builtin_amdgcn_exp2f(acc[mi][0][2 * rp + 1] * inv) +
                   __builtin_amdgcn_exp2f(acc[mi][1][2 * rp + 1] * inv);
#pragma unroll
        for (int off = 1; off < 32; off <<= 1) {
          v0 += __shfl_xor(v0, off);
          v1 += __shfl_xor(v1, off);
        }
        if (l5 == 0) {
          int r0 = ((2 * rp) & 3) + 8 * (rp >> 1) + 4 * hi + mi * 32;
          pss[wr][wc][r0] = v0;
          pss[wr][wc][r0 + 1] = v1;
        }
      }
  } else {
#pragma unroll
    for (int mi = 0; mi < 2; ++mi)
#pragma unroll
      for (int rp = 0; rp < 8; ++rp) {
        float st0 = 0.f, st1 = 0.f, at0 = 0.f, at1 = 0.f;
#pragma unroll
        for (int ni = 0; ni < 2; ++ni) {
          uint u = exch[(((wq * 2 + mi) * 2 + ni) * 8 + rp) * 64 + lane];
          float sv0 = __uint_as_float(u << 16);
          float sv1 = __uint_as_float(u & 0xffff0000u);
          float t0 = acc[mi][ni][2 * rp] * inv;
          float t1 = acc[mi][ni][2 * rp + 1] * inv;
          float e0 = __builtin_amdgcn_exp2f(t0);
          float e1 = __builtin_amdgcn_exp2f(t1);
          st0 += e0; st1 += e1;
          at0 += e0 * (t0 - sv0);
          at1 += e1 * (t1 - sv1);
        }
#pragma unroll
        for (int off = 1; off < 32; off <<= 1) {
          st0 += __shfl_xor(st0, off);
          st1 += __shfl_xor(st1, off);
          at0 += __shfl_xor(at0, off);
          at1 += __shfl_xor(at1, off);
        }
        if (l5 == 0) {
          int r0 = ((2 * rp) & 3) + 8 * (rp >> 1) + 4 * hi + mi * 32;
          pst[wr][wc][r0] = st0;
          pst[wr][wc][r0 + 1] = st1;
          pat[wr][wc][r0] = at0;
          pat[wr][wc][r0 + 1] = at1;
        }
      }
  }
  __syncthreads();

  // combine wc pairs, one atomic per row per quantity (same count as r6)
  if (wc == 0) {
    int row = row0 + wr * 64 + lane;
    if (mat == 0) {
      float ss = pss[wr][0][lane] + pss[wr][1][lane];
      atomicAdd(&stats[(size_t)row * 3 + 0], ss);
    } else {
      float st = pst[wr][0][lane] + pst[wr][1][lane];
      float at = pat[wr][0][lane] + pat[wr][1][lane];
      atomicAdd(&stats[(size_t)row * 3 + 1], st);
      atomicAdd(&stats[(size_t)row * 3 + 2], at);
    }
  }
}

// ---------------- finalize: sum spread copies, per-row loss + global sum ----------------
__global__ void finalize(const float* __restrict__ stats32, const float* __restrict__ tgt,
                         const float* __restrict__ cec, const float* __restrict__ klc,
                         float* __restrict__ out) {
  __shared__ float red[16];
  int tid = threadIdx.x;  // 1024 threads
  float acc = 0.f;
  for (int r = tid; r < B_; r += 1024) {
    float ss = 0.f, st = 0.f, at = 0.f;
#pragma unroll
    for (int j = 0; j < NCOPY; ++j) {
      const float* s = stats32 + ((size_t)j * B_ + r) * 3;
      ss += s[0]; st += s[1]; at += s[2];
    }
    float s_lse = LN2 * __builtin_amdgcn_logf(ss);
    float t_lse = LN2 * __builtin_amdgcn_logf(st);
    float kl = s_lse - t_lse + LN2 * at / st;
    float ce = s_lse - tgt[r];
    acc += cec[r] * ce + klc[r] * kl;
  }
#pragma unroll
  for (int off = 1; off < 64; off <<= 1) acc += __shfl_xor(acc, off);
  if ((tid & 63) == 0) red[tid >> 6] = acc;
  __syncthreads();
  if (tid == 0) {
    float s = 0.f;
#pragma unroll
    for (int i = 0; i < 16; ++i) s += red[i];
    out[0] = s;
  }
}

extern "C" void kernel_launch(void* const* d_in, const int* in_sizes, int n_in,
                              void* d_out, int out_size, void* d_ws, size_t ws_size,
                              hipStream_t stream) {
  const float* sh = (const float*)d_in[0];
  const float* sc = (const float*)d_in[1];
  const float* th = (const float*)d_in[2];
  const float* tc = (const float*)d_in[3];
  const float* cec = (const float*)d_in[4];
  const float* klc = (const float*)d_in[5];
  const int* targets = (const int*)d_in[6];
  float* out = (float*)d_out;

  char* ws = (char*)d_ws;
  u8* SC8t = (u8*)ws;                               // 25,755,648 (transposed)
  u8* TC8t = SC8t + (size_t)V_ * D_;                // 25,755,648 (transposed)
  u8* SH8 = TC8t + (size_t)V_ * D_;                 // 1,048,576
  u8* TH8 = SH8 + (size_t)B_ * D_;                  // 1,048,576
  float* stats32 = (float*)(TH8 + (size_t)B_ * D_); // 786,432 B: [32][2048][3]
  float* tgt = stats32 + (size_t)NCOPY * B_ * 3;    // 8 KB
  // total ~54.4 MB, within confirmed ws_size >= 55.7 MB

  hipMemsetAsync(stats32, 0, (size_t)NCOPY * B_ * 3 * sizeof(float), stream);
  const float hscale = 16.0f * LOG2E;
  const float cscale = 16.0f;
  const int nchunk = V_ * D_ / 32;  // 804,864 = 256 * 3144
  cast8t_kernel<<<3144, 256, 0, stream>>>(sc, (uint4*)SC8t, cscale, nchunk);
  cast8t_kernel<<<3144, 256, 0, stream>>>(tc, (uint4*)TC8t, cscale, nchunk);
  cast8_kernel<<<256, 256, 0, stream>>>(sh, (uint2*)SH8, hscale, B_ * D_ / 8);
  cast8_kernel<<<256, 256, 0, stream>>>(th, (uint2*)TH8, hscale, B_ * D_ / 8);
  tgt_kernel<<<512, 256, 0, stream>>>(sh, sc, targets, tgt);

  lce_main<<<NWG, 512, 0, stream>>>(SH8, TH8, SC8t, TC8t, stats32);
  finalize<<<1, 1024, 0, stream>>>(stats32, tgt, cec, klc, out);
}